// Round 1
// baseline (554.599 us; speedup 1.0000x reference)
//
#include <hip/hip_runtime.h>
#include <hip/hip_bf16.h>

// Problem constants
#define T_    512
#define FREQ_ 64
#define CIN_  128
#define OC1   384   // 3*HID
#define NH    8
#define HD    1024  // per-head dim = 16 channels * 64 freq

using sh8  = __attribute__((ext_vector_type(8))) short;  // 8 bf16 (4 VGPRs) MFMA operand
using sh4  = __attribute__((ext_vector_type(4))) short;
using fx4  = __attribute__((ext_vector_type(4))) float;  // MFMA accumulator

__device__ __forceinline__ short bf16r(float x) {
  union { float f; unsigned u; } v; v.f = x;
  unsigned u = v.u;
  u += 0x7fffu + ((u >> 16) & 1u);   // RNE
  return (short)(u >> 16);
}

__device__ __forceinline__ fx4 mfma_bf16(sh8 a, sh8 b, fx4 c) {
  return __builtin_amdgcn_mfma_f32_16x16x32_bf16(a, b, c, 0, 0, 0);
}

// ---------------------------------------------------------------------------
// K0: convert conv weights f32 -> bf16 once (both fit in L2, reused by all blocks)
__global__ void k_prep(const float* __restrict__ qw, const float* __restrict__ pw,
                       short* __restrict__ qwb, short* __restrict__ pwb) {
  const int i = blockIdx.x * 256 + threadIdx.x;
  if (i < OC1 * CIN_) qwb[i] = bf16r(qw[i]);
  if (i < 128 * 128)  pwb[i] = bf16r(pw[i]);
}

// ---------------------------------------------------------------------------
// K1: per (b,t): Y[384,64] = W[384,128] @ X[128,64]; bias+PReLU+LN over (384x64);
//     scatter into Q[bh][t][d], K[bh][t][d], Vt[bh][d][t] (bf16).
__global__ __launch_bounds__(512) void k_qkv(
    const float* __restrict__ x, const short* __restrict__ wb,
    const float* __restrict__ bias, const float* __restrict__ alphap,
    const float* __restrict__ gamma, const float* __restrict__ beta,
    short* __restrict__ Qo, short* __restrict__ Ko, short* __restrict__ Vt)
{
  const int bt = blockIdx.x;
  const int b = bt >> 9, t = bt & 511;
  const int tid = threadIdx.x, lane = tid & 63, w = tid >> 6;

  // smem: first 16KB = Xs[f][c] (XOR-swizzled 16B slots); reused as ybuf[o][f] (48KB) after MFMA.
  __shared__ short smem[OC1 * 64];
  __shared__ float red[18];
  short* Xs = smem;
  short* ybuf = smem;

  // stage X: x[b,c,f,t] -> Xs[f][c] bf16 (scattered global reads; lines reused by t-adjacent blocks)
  for (int i = tid; i < CIN_ * FREQ_; i += 512) {
    const int c = i >> 6, f = i & 63;
    const float v = x[((b * CIN_ + c) * FREQ_ + f) * T_ + t];
    Xs[(f * 256 + ((2 * c) ^ ((f & 7) << 4))) >> 1] = bf16r(v);
  }
  __syncthreads();

  const float alpha = alphap[0];
  const fx4 z4 = {0.f, 0.f, 0.f, 0.f};
  fx4 acc[3][4];
  for (int mi = 0; mi < 3; ++mi)
    for (int ni = 0; ni < 4; ++ni) acc[mi][ni] = z4;

  // wave w owns m-tiles w*3..w*3+2 (o), all 4 n-tiles (f). K=128 -> 4 steps of 32.
  #pragma unroll
  for (int ks = 0; ks < 4; ++ks) {
    sh8 a[3];
    #pragma unroll
    for (int mi = 0; mi < 3; ++mi) {
      const int o = (w * 3 + mi) * 16 + (lane & 15);
      const int k = ks * 32 + (lane >> 4) * 8;
      a[mi] = *(const sh8*)(wb + o * CIN_ + k);   // W bf16, L2-hot
    }
    #pragma unroll
    for (int ni = 0; ni < 4; ++ni) {
      const int f = ni * 16 + (lane & 15);
      const int kb = (ks * 32 + (lane >> 4) * 8) * 2;
      const sh8 bf = *(const sh8*)((const char*)Xs + f * 256 + (kb ^ ((f & 7) << 4)));
      #pragma unroll
      for (int mi = 0; mi < 3; ++mi)
        acc[mi][ni] = mfma_bf16(a[mi], bf, acc[mi][ni]);
    }
  }

  // bias + PReLU (in place) + stats
  float s0 = 0.f, s1 = 0.f;
  #pragma unroll
  for (int mi = 0; mi < 3; ++mi) {
    const int ob = (w * 3 + mi) * 16 + (lane >> 4) * 4;
    #pragma unroll
    for (int ni = 0; ni < 4; ++ni)
      #pragma unroll
      for (int r = 0; r < 4; ++r) {
        float v = acc[mi][ni][r] + bias[ob + r];
        v = (v >= 0.f) ? v : alpha * v;
        acc[mi][ni][r] = v;
        s0 += v; s1 += v * v;
      }
  }
  #pragma unroll
  for (int off = 32; off > 0; off >>= 1) { s0 += __shfl_down(s0, off); s1 += __shfl_down(s1, off); }
  if (lane == 0) { red[w * 2] = s0; red[w * 2 + 1] = s1; }
  __syncthreads();   // also orders all Xs reads before ybuf overwrites
  if (tid == 0) {
    float a0 = 0.f, a1 = 0.f;
    for (int i2 = 0; i2 < 8; ++i2) { a0 += red[2 * i2]; a1 += red[2 * i2 + 1]; }
    const float mu = a0 / (float)(OC1 * 64);
    const float var = a1 / (float)(OC1 * 64) - mu * mu;
    red[16] = mu; red[17] = rsqrtf(var + 1e-5f);
  }
  __syncthreads();
  const float mu = red[16], rstd = red[17];

  // normalize -> ybuf[o][f] bf16
  #pragma unroll
  for (int mi = 0; mi < 3; ++mi) {
    const int ob = (w * 3 + mi) * 16 + (lane >> 4) * 4;
    #pragma unroll
    for (int ni = 0; ni < 4; ++ni) {
      const int f = ni * 16 + (lane & 15);
      #pragma unroll
      for (int r = 0; r < 4; ++r) {
        const int o = ob + r;
        const float zz = (acc[mi][ni][r] - mu) * rstd * gamma[o * 64 + f] + beta[o * 64 + f];
        ybuf[o * 64 + f] = bf16r(zz);
      }
    }
  }
  __syncthreads();

  // scatter: o -> (h = o/48, sect = (o%48)/16, cl = o%16), d = cl*64+f
  const int bh0 = b * NH;
  for (int i = tid; i < OC1 * 32; i += 512) {
    const int o = i >> 5, pr = i & 31;
    const unsigned v = *(const unsigned*)&ybuf[o * 64 + pr * 2];
    const int h = o / 48, rr = o % 48;
    const int sect = rr >> 4, cl = rr & 15;
    const int d = cl * 64 + pr * 2;
    if (sect == 0)      *(unsigned*)(Qo + (((size_t)(bh0 + h)) * T_ + t) * HD + d) = v;
    else if (sect == 1) *(unsigned*)(Ko + (((size_t)(bh0 + h)) * T_ + t) * HD + d) = v;
    else {  // V transposed: Vt[bh][d][t] so PV is a B^T-GEMM
      Vt[(((size_t)(bh0 + h)) * HD + d) * T_ + t]     = (short)(v & 0xffffu);
      Vt[(((size_t)(bh0 + h)) * HD + d + 1) * T_ + t] = (short)(v >> 16);
    }
  }
}

// ---------------------------------------------------------------------------
// K2: S[bh][q][k] = (Q . K)/32 for k-tile <= q-tile only. 128x128 tile, 4 waves.
__global__ __launch_bounds__(256) void k_qk(
    const short* __restrict__ Q, const short* __restrict__ K, float* __restrict__ S)
{
  const int bid = blockIdx.x;
  const int bh = bid / 10;
  const int j = bid - bh * 10;                       // 10 lower-tri (qi,ki) pairs
  const int qi = (j >= 6) ? 3 : (j >= 3) ? 2 : (j >= 1) ? 1 : 0;
  const int ki = j - qi * (qi + 1) / 2;

  const int tid = threadIdx.x, lane = tid & 63, w = tid >> 6;
  const int wm = w >> 1, wn = w & 1;

  __shared__ short Qs[128 * 32];
  __shared__ short Ks[128 * 32];

  const short* Qg = Q + ((size_t)bh * T_ + qi * 128) * HD;
  const short* Kg = K + ((size_t)bh * T_ + ki * 128) * HD;

  const fx4 z4 = {0.f, 0.f, 0.f, 0.f};
  fx4 acc[4][4];
  for (int mi = 0; mi < 4; ++mi) for (int ni = 0; ni < 4; ++ni) acc[mi][ni] = z4;

  for (int ks = 0; ks < 32; ++ks) {                  // K=1024, BK=32
    __syncthreads();
    #pragma unroll
    for (int c2 = 0; c2 < 2; ++c2) {
      const int chunk = tid + c2 * 256;
      const int row = chunk >> 2, part = chunk & 3;
      *(sh8*)&Qs[row * 32 + part * 8] = *(const sh8*)(Qg + (size_t)row * HD + ks * 32 + part * 8);
      *(sh8*)&Ks[row * 32 + part * 8] = *(const sh8*)(Kg + (size_t)row * HD + ks * 32 + part * 8);
    }
    __syncthreads();
    sh8 a[4], bf[4];
    #pragma unroll
    for (int mi = 0; mi < 4; ++mi)
      a[mi] = *(const sh8*)&Qs[(wm * 64 + mi * 16 + (lane & 15)) * 32 + (lane >> 4) * 8];
    #pragma unroll
    for (int ni = 0; ni < 4; ++ni)
      bf[ni] = *(const sh8*)&Ks[(wn * 64 + ni * 16 + (lane & 15)) * 32 + (lane >> 4) * 8];
    #pragma unroll
    for (int mi = 0; mi < 4; ++mi)
      #pragma unroll
      for (int ni = 0; ni < 4; ++ni)
        acc[mi][ni] = mfma_bf16(a[mi], bf[ni], acc[mi][ni]);
  }

  float* Sg = S + (size_t)bh * T_ * T_;
  const int q0 = qi * 128 + wm * 64, k0 = ki * 128 + wn * 64;
  #pragma unroll
  for (int mi = 0; mi < 4; ++mi)
    #pragma unroll
    for (int ni = 0; ni < 4; ++ni) {
      const int q = q0 + mi * 16 + (lane >> 4) * 4;
      const int kc = k0 + ni * 16 + (lane & 15);
      #pragma unroll
      for (int r = 0; r < 4; ++r)
        Sg[(size_t)(q + r) * T_ + kc] = acc[mi][ni][r] * 0.03125f;  // * hd^-0.5
    }
}

// ---------------------------------------------------------------------------
// K3: causal softmax in place; zeros above the diagonal (tiles K2 never wrote
//     are never read). One wave per row, 4 rows/block.
__global__ __launch_bounds__(256) void k_softmax(float* __restrict__ S)
{
  const int row = blockIdx.x * 4 + (threadIdx.x >> 6);
  const int lane = threadIdx.x & 63;
  const int bh = row >> 9, q = row & 511;
  float* Sr = S + (size_t)bh * T_ * T_ + (size_t)q * T_;
  const int n = q + 1;
  float v[8];
  float mx = -1e30f;
  #pragma unroll
  for (int i = 0; i < 8; ++i) {
    const int k = lane + i * 64;
    v[i] = (k < n) ? Sr[k] : -1e30f;
    mx = fmaxf(mx, v[i]);
  }
  #pragma unroll
  for (int off = 32; off > 0; off >>= 1) mx = fmaxf(mx, __shfl_xor(mx, off));
  float sum = 0.f;
  #pragma unroll
  for (int i = 0; i < 8; ++i) {
    const float e = (v[i] > -1e29f) ? __expf(v[i] - mx) : 0.f;
    v[i] = e; sum += e;
  }
  #pragma unroll
  for (int off = 32; off > 0; off >>= 1) sum += __shfl_xor(sum, off);
  const float inv = 1.f / sum;
  #pragma unroll
  for (int i = 0; i < 8; ++i) Sr[lane + i * 64] = v[i] * inv;   // k>q -> 0
}

// ---------------------------------------------------------------------------
// K4: ctx = P @ V per (bh, q-tile, d-tile); epilogue restages tile through LDS
//     and writes the scrambled c[b][C][t2][f2] layout in contiguous 128B runs.
__global__ __launch_bounds__(256) void k_pv(
    const float* __restrict__ S, const short* __restrict__ Vt, short* __restrict__ Cs)
{
  const int bid = blockIdx.x;
  const int bh = bid >> 5;
  const int rr0 = bid & 31;
  const int qi = rr0 >> 3, dt = rr0 & 7;
  const int tid = threadIdx.x, lane = tid & 63, w = tid >> 6;
  const int wm = w >> 1, wn = w & 1;

  __shared__ short Ps[128 * 32];
  __shared__ short Vs[128 * 32];
  __shared__ short ctile[128 * 128];   // [dl][ql], 16B-slot XOR swizzle

  const float* Sg = S + (size_t)bh * T_ * T_ + (size_t)(qi * 128) * T_;
  const short* Vg = Vt + ((size_t)bh * HD + dt * 128) * T_;

  const fx4 z4 = {0.f, 0.f, 0.f, 0.f};
  fx4 acc[4][4];
  for (int mi = 0; mi < 4; ++mi) for (int ni = 0; ni < 4; ++ni) acc[mi][ni] = z4;

  const int nks = (qi + 1) * 4;        // causal: K only up to (qi+1)*128
  for (int ks = 0; ks < nks; ++ks) {
    __syncthreads();
    #pragma unroll
    for (int c2 = 0; c2 < 4; ++c2) {   // P f32 -> bf16 stage
      const int chunk = tid + c2 * 256;
      const int row = chunk >> 3, part = chunk & 7;
      const float4 fv = *(const float4*)(Sg + (size_t)row * T_ + ks * 32 + part * 4);
      sh4 sv; sv[0] = bf16r(fv.x); sv[1] = bf16r(fv.y); sv[2] = bf16r(fv.z); sv[3] = bf16r(fv.w);
      *(sh4*)&Ps[row * 32 + part * 4] = sv;
    }
    #pragma unroll
    for (int c2 = 0; c2 < 2; ++c2) {   // Vt rows (d) stage
      const int chunk = tid + c2 * 256;
      const int row = chunk >> 2, part = chunk & 3;
      *(sh8*)&Vs[row * 32 + part * 8] = *(const sh8*)(Vg + (size_t)row * T_ + ks * 32 + part * 8);
    }
    __syncthreads();
    sh8 a[4], bf[4];
    #pragma unroll
    for (int mi = 0; mi < 4; ++mi)
      a[mi] = *(const sh8*)&Ps[(wm * 64 + mi * 16 + (lane & 15)) * 32 + (lane >> 4) * 8];
    #pragma unroll
    for (int ni = 0; ni < 4; ++ni)
      bf[ni] = *(const sh8*)&Vs[(wn * 64 + ni * 16 + (lane & 15)) * 32 + (lane >> 4) * 8];
    #pragma unroll
    for (int mi = 0; mi < 4; ++mi)
      #pragma unroll
      for (int ni = 0; ni < 4; ++ni)
        acc[mi][ni] = mfma_bf16(a[mi], bf[ni], acc[mi][ni]);
  }

  // acc -> ctile[dl][ql] (bf16, swizzled)
  #pragma unroll
  for (int mi = 0; mi < 4; ++mi)
    #pragma unroll
    for (int ni = 0; ni < 4; ++ni) {
      const int ql = wm * 64 + mi * 16 + (lane >> 4) * 4;
      const int dl = wn * 64 + ni * 16 + (lane & 15);
      const int swz = (dl & 7) << 4;
      #pragma unroll
      for (int r = 0; r < 4; ++r)
        ctile[(dl * 256 + ((2 * (ql + r)) ^ swz)) >> 1] = bf16r(acc[mi][ni][r]);
    }
  __syncthreads();

  // 256 runs: (cl_loc, f, tg_loc) -> contiguous f2 in [0,64)
  const int b = bh >> 3, h = bh & 7;
  const int cl_loc = tid >> 7, f = (tid >> 1) & 63, tg_loc = tid & 1;
  const int C = h * 16 + dt * 2 + cl_loc;
  const int t2 = f * 8 + qi * 2 + tg_loc;
  const int dl = cl_loc * 64 + f;
  const int swz = (dl & 7) << 4;
  short* dst = Cs + (((size_t)b * 128 + C) * T_ + t2) * 64;
  #pragma unroll
  for (int jj = 0; jj < 8; ++jj) {
    const sh8 vv = *(const sh8*)((const char*)ctile + dl * 256 + ((tg_loc * 128 + jj * 16) ^ swz));
    *(sh8*)(dst + jj * 8) = vv;
  }
}

// ---------------------------------------------------------------------------
// K5: per (b,t2): Y[128,64] = Wp[128,128] @ X2[128,64]; bias+PReLU+LN(128x64);
//     out[b][o][f2][t2] f32.
__global__ __launch_bounds__(512) void k_proj(
    const short* __restrict__ Cs, const short* __restrict__ wb,
    const float* __restrict__ bias, const float* __restrict__ alphap,
    const float* __restrict__ gamma, const float* __restrict__ beta,
    float* __restrict__ out)
{
  const int bt = blockIdx.x;
  const int b = bt >> 9, t2 = bt & 511;
  const int tid = threadIdx.x, lane = tid & 63, w = tid >> 6;

  __shared__ short Xs[64 * 128];   // [f2][C] swizzled
  __shared__ float red[18];

  for (int i = tid; i < 128 * 64; i += 512) {   // coalesced bf16 row reads of Cs
    const int C = i >> 6, f2 = i & 63;
    const short v = Cs[(((size_t)b * 128 + C) * T_ + t2) * 64 + f2];
    Xs[(f2 * 256 + ((2 * C) ^ ((f2 & 7) << 4))) >> 1] = v;
  }
  __syncthreads();

  const float alpha = alphap[0];
  const fx4 z4 = {0.f, 0.f, 0.f, 0.f};
  fx4 acc[4];
  for (int ni = 0; ni < 4; ++ni) acc[ni] = z4;

  #pragma unroll
  for (int ks = 0; ks < 4; ++ks) {
    const int o = w * 16 + (lane & 15);
    const int k = ks * 32 + (lane >> 4) * 8;
    const sh8 a = *(const sh8*)(wb + o * 128 + k);
    #pragma unroll
    for (int ni = 0; ni < 4; ++ni) {
      const int f = ni * 16 + (lane & 15);
      const sh8 bf = *(const sh8*)((const char*)Xs + f * 256 + ((k * 2) ^ ((f & 7) << 4)));
      acc[ni] = mfma_bf16(a, bf, acc[ni]);
    }
  }

  float s0 = 0.f, s1 = 0.f;
  const int ob = w * 16 + (lane >> 4) * 4;
  #pragma unroll
  for (int ni = 0; ni < 4; ++ni)
    #pragma unroll
    for (int r = 0; r < 4; ++r) {
      float v = acc[ni][r] + bias[ob + r];
      v = (v >= 0.f) ? v : alpha * v;
      acc[ni][r] = v;
      s0 += v; s1 += v * v;
    }
  #pragma unroll
  for (int off = 32; off > 0; off >>= 1) { s0 += __shfl_down(s0, off); s1 += __shfl_down(s1, off); }
  if (lane == 0) { red[w * 2] = s0; red[w * 2 + 1] = s1; }
  __syncthreads();
  if (tid == 0) {
    float a0 = 0.f, a1 = 0.f;
    for (int i2 = 0; i2 < 8; ++i2) { a0 += red[2 * i2]; a1 += red[2 * i2 + 1]; }
    const float mu = a0 / 8192.f;
    const float var = a1 / 8192.f - mu * mu;
    red[16] = mu; red[17] = rsqrtf(var + 1e-5f);
  }
  __syncthreads();
  const float mu = red[16], rstd = red[17];

  #pragma unroll
  for (int ni = 0; ni < 4; ++ni) {
    const int f2 = ni * 16 + (lane & 15);
    #pragma unroll
    for (int r = 0; r < 4; ++r) {
      const int o = ob + r;
      const float zz = (acc[ni][r] - mu) * rstd * gamma[o * 64 + f2] + beta[o * 64 + f2];
      out[((size_t)(b * 128 + o) * 64 + f2) * T_ + t2] = zz;
    }
  }
}

// ---------------------------------------------------------------------------
extern "C" void kernel_launch(void* const* d_in, const int* in_sizes, int n_in,
                              void* d_out, int out_size, void* d_ws, size_t ws_size,
                              hipStream_t stream) {
  (void)in_sizes; (void)n_in; (void)out_size;
  const float* x          = (const float*)d_in[0];
  const float* qkv_w      = (const float*)d_in[1];
  const float* qkv_b      = (const float*)d_in[2];
  const float* qkv_alpha  = (const float*)d_in[3];
  const float* qkv_gamma  = (const float*)d_in[4];
  const float* qkv_beta   = (const float*)d_in[5];
  const float* proj_w     = (const float*)d_in[6];
  const float* proj_b     = (const float*)d_in[7];
  const float* proj_alpha = (const float*)d_in[8];
  const float* proj_gamma = (const float*)d_in[9];
  const float* proj_beta  = (const float*)d_in[10];
  float* out = (float*)d_out;

  // workspace layout (bytes); total need = 167,903,232 (~160.1 MB)
  char* ws = (char*)d_ws;
  short* Qb  = (short*)(ws + 0);              // [32][512][1024] bf16, 33.5MB
  short* Kb  = (short*)(ws + 33554432);       // same
  short* Vt  = (short*)(ws + 67108864);       // [32][1024][512] bf16 (transposed)
  float* S   = (float*)(ws + 100663296);      // [32][512][512] f32
  short* Cs  = (short*)(ws + 134217728);      // [4][128][512][64] bf16 (scrambled c)
  short* qwb = (short*)(ws + 167772160);      // qkv_w bf16
  short* pwb = (short*)(ws + 167870464);      // proj_w bf16
  if (ws_size < 167903232u) return;           // fail loudly (output stays poisoned)

  k_prep<<<192, 256, 0, stream>>>(qkv_w, proj_w, qwb, pwb);
  k_qkv<<<2048, 512, 0, stream>>>(x, qwb, qkv_b, qkv_alpha, qkv_gamma, qkv_beta, Qb, Kb, Vt);
  k_qk<<<320, 256, 0, stream>>>(Qb, Kb, S);
  k_softmax<<<4096, 256, 0, stream>>>(S);
  k_pv<<<1024, 256, 0, stream>>>(S, Vt, Cs);
  k_proj<<<2048, 512, 0, stream>>>(Cs, pwb, proj_b, proj_alpha, proj_gamma, proj_beta, out);
}

// Round 2
// 279.028 us; speedup vs baseline: 1.9876x; 1.9876x over previous
//
#include <hip/hip_runtime.h>
#include <hip/hip_bf16.h>

#define T_    512
#define CIN_  128
#define OC1   384
#define NH    8
#define HD    1024

using sh8 = __attribute__((ext_vector_type(8))) short;  // 8 bf16
using fx4 = __attribute__((ext_vector_type(4))) float;  // MFMA acc

__device__ __forceinline__ short bf16r(float x) {
  union { float f; unsigned u; } v; v.f = x;
  unsigned u = v.u;
  u += 0x7fffu + ((u >> 16) & 1u);   // RNE
  return (short)(u >> 16);
}
__device__ __forceinline__ float b2f(short s) {
  union { float f; unsigned u; } v; v.u = ((unsigned)(unsigned short)s) << 16;
  return v.f;
}
__device__ __forceinline__ fx4 mfma_bf16(sh8 a, sh8 b, fx4 c) {
  return __builtin_amdgcn_mfma_f32_16x16x32_bf16(a, b, c, 0, 0, 0);
}

// ---------------------------------------------------------------------------
// K0: weights f32 -> bf16
__global__ void k_prep(const float* __restrict__ qw, const float* __restrict__ pw,
                       short* __restrict__ qwb, short* __restrict__ pwb) {
  const int i = blockIdx.x * 256 + threadIdx.x;
  if (i < OC1 * CIN_) qwb[i] = bf16r(qw[i]);
  if (i < 128 * 128)  pwb[i] = bf16r(pw[i]);
}

// ---------------------------------------------------------------------------
// kA: per (b, f, t-tile 128): Y[384,128t] = W @ X; bias+PReLU; column partial
//     sums -> Pstat[2][4][64][512]; pre-norm bf16 -> Qt/Kt/Vt [bh][d][t].
__global__ __launch_bounds__(512) void kA_qkv(
    const float* __restrict__ x, const short* __restrict__ wb,
    const float* __restrict__ bias, const float* __restrict__ alphap,
    short* __restrict__ Qt, short* __restrict__ Kt, short* __restrict__ Vt,
    float* __restrict__ Pstat)
{
  const int bid = blockIdx.x;
  const int b = bid >> 8, f = (bid >> 2) & 63, tt = bid & 3;
  const int tid = threadIdx.x, lane = tid & 63, w = tid >> 6;

  __shared__ short Xs[128 * 128];            // [t][c] bf16, XOR-swizzled 16B slots
  __shared__ float psum[8 * 8 * 16 * 2];     // [w][ni][lane16][s]

  // stage X: coalesced float4 along t
  {
    const int c = tid & 127, tg = tid >> 7;
    const float* xp = x + ((size_t)(b * 128 + c) * 64 + f) * 512 + tt * 128 + tg * 32;
    #pragma unroll
    for (int i = 0; i < 8; ++i) {
      const float4 fv = *(const float4*)(xp + i * 4);
      #pragma unroll
      for (int j = 0; j < 4; ++j) {
        const int t = tg * 32 + i * 4 + j;
        *((short*)((char*)Xs + t * 256 + ((2 * c) ^ ((t & 7) << 4)))) = bf16r((&fv.x)[j]);
      }
    }
  }
  __syncthreads();

  const float alpha = alphap[0];
  fx4 acc[3][8];
  #pragma unroll
  for (int mi = 0; mi < 3; ++mi)
    #pragma unroll
    for (int ni = 0; ni < 8; ++ni) acc[mi][ni] = fx4{0.f, 0.f, 0.f, 0.f};

  // wave w owns o in [w*48, w*48+48): h = w, sect = mi. K=128 -> 4 steps.
  #pragma unroll
  for (int ks = 0; ks < 4; ++ks) {
    sh8 a[3];
    #pragma unroll
    for (int mi = 0; mi < 3; ++mi) {
      const int o = w * 48 + mi * 16 + (lane & 15);
      a[mi] = *(const sh8*)(wb + o * 128 + ks * 32 + (lane >> 4) * 8);   // L2-hot
    }
    #pragma unroll
    for (int ni = 0; ni < 8; ++ni) {
      const int t = ni * 16 + (lane & 15);
      const int kb = ks * 64 + (lane >> 4) * 16;
      const sh8 bf = *(const sh8*)((const char*)Xs + t * 256 + (kb ^ ((t & 7) << 4)));
      #pragma unroll
      for (int mi = 0; mi < 3; ++mi)
        acc[mi][ni] = mfma_bf16(a[mi], bf, acc[mi][ni]);
    }
  }

  // bias + PReLU + per-column partials
  float s0[8], s1[8];
  #pragma unroll
  for (int ni = 0; ni < 8; ++ni) { s0[ni] = 0.f; s1[ni] = 0.f; }
  #pragma unroll
  for (int mi = 0; mi < 3; ++mi)
    #pragma unroll
    for (int r = 0; r < 4; ++r) {
      const int o = w * 48 + mi * 16 + (lane >> 4) * 4 + r;
      const float bo = bias[o];
      #pragma unroll
      for (int ni = 0; ni < 8; ++ni) {
        float v = acc[mi][ni][r] + bo;
        v = (v >= 0.f) ? v : alpha * v;
        acc[mi][ni][r] = v;
        s0[ni] += v; s1[ni] += v * v;
      }
    }
  #pragma unroll
  for (int ni = 0; ni < 8; ++ni) {
    float a0 = s0[ni], a1 = s1[ni];
    a0 += __shfl_down(a0, 32); a1 += __shfl_down(a1, 32);
    a0 += __shfl_down(a0, 16); a1 += __shfl_down(a1, 16);
    if (lane < 16) {
      psum[((w * 8 + ni) * 16 + lane) * 2 + 0] = a0;
      psum[((w * 8 + ni) * 16 + lane) * 2 + 1] = a1;
    }
  }
  __syncthreads();
  if (tid < 256) {
    const int col = tid & 127, s = tid >> 7;
    const int ni = col >> 4, l = col & 15;
    float a0 = 0.f;
    #pragma unroll
    for (int ww = 0; ww < 8; ++ww) a0 += psum[((ww * 8 + ni) * 16 + l) * 2 + s];
    Pstat[(size_t)s * 131072 + (size_t)b * 32768 + (size_t)f * 512 + tt * 128 + col] = a0;
  }

  // pre-norm stores: Qt/Kt/Vt[bh][d][t], 32B t-runs per 16-lane group
  const int bh = b * 8 + w;
  #pragma unroll
  for (int mi = 0; mi < 3; ++mi) {
    short* dst = (mi == 0) ? Qt : (mi == 1) ? Kt : Vt;
    #pragma unroll
    for (int r = 0; r < 4; ++r) {
      const int cl = (lane >> 4) * 4 + r;
      const int d = cl * 64 + f;
      short* rowp = dst + ((size_t)bh * 1024 + d) * 512 + tt * 128;
      #pragma unroll
      for (int ni = 0; ni < 8; ++ni)
        rowp[ni * 16 + (lane & 15)] = bf16r(acc[mi][ni][r]);
    }
  }
}

// ---------------------------------------------------------------------------
// kB: finalize stats per (b,t); normalize. Q/K: LDS-transpose Qt/Kt[d][t] ->
//     Q/K[bh][t][d] (2KB rows). V: normalize Vt in place ([d][t] kept for PV).
__global__ __launch_bounds__(256) void kB_norm(
    const short* __restrict__ Qt, const short* __restrict__ Kt, short* __restrict__ Vt,
    const float* __restrict__ Pstat,
    const float* __restrict__ gamma, const float* __restrict__ beta,
    short* __restrict__ Q, short* __restrict__ K)
{
  const int bid = blockIdx.x;
  const int bh = bid >> 4, tc = bid & 15;
  const int b = bh >> 3, h = bh & 7;
  const int tid = threadIdx.x, lane = tid & 63, w = tid >> 6;
  const int t0 = tc * 32;

  __shared__ short Lt[32 * 512];   // [t_local][d_local] swizzled (1KB rows)
  __shared__ float stats[32][2];

  // per-(b,t) stats: wave w -> t_local w*8..w*8+7; lane = f
  #pragma unroll
  for (int k = 0; k < 8; ++k) {
    const int tl = w * 8 + k;
    const int t = t0 + tl;
    float p0 = Pstat[(size_t)b * 32768 + (size_t)lane * 512 + t];
    float p1 = Pstat[131072 + (size_t)b * 32768 + (size_t)lane * 512 + t];
    #pragma unroll
    for (int off = 32; off > 0; off >>= 1) { p0 += __shfl_down(p0, off); p1 += __shfl_down(p1, off); }
    if (lane == 0) {
      const float mu = p0 * (1.f / 24576.f);
      const float var = p1 * (1.f / 24576.f) - mu * mu;
      stats[tl][0] = mu;
      stats[tl][1] = rsqrtf(var + 1e-5f);
    }
  }
  __syncthreads();

  // Q and K passes: 2 sects x 2 d-halves through 32KB LDS
  for (int sect = 0; sect < 2; ++sect) {
    const short* src = sect ? Kt : Qt;
    short* dstq = sect ? K : Q;
    for (int dh = 0; dh < 2; ++dh) {
      __syncthreads();
      #pragma unroll
      for (int rr = 0; rr < 2; ++rr) {
        const int dl = tid + rr * 256;
        const int d = dh * 512 + dl;
        const int gi = (h * 48 + sect * 16 + (d >> 6)) * 64 + (d & 63);
        const float g = gamma[gi], be = beta[gi];
        const short* srow = src + ((size_t)bh * 1024 + d) * 512 + t0;
        #pragma unroll
        for (int i = 0; i < 4; ++i) {
          const sh8 vv = *(const sh8*)(srow + i * 8);
          #pragma unroll
          for (int j = 0; j < 8; ++j) {
            const int tl = i * 8 + j;
            const float z = (b2f(vv[j]) - stats[tl][0]) * stats[tl][1] * g + be;
            *((short*)((char*)Lt + tl * 1024 + ((2 * dl) ^ ((tl & 7) << 4)))) = bf16r(z);
          }
        }
      }
      __syncthreads();
      const int tl = tid >> 3;
      short* orow = dstq + ((size_t)bh * 512 + (t0 + tl)) * 1024 + dh * 512;
      #pragma unroll
      for (int it = 0; it < 8; ++it) {
        const int c16 = (tid & 7) + it * 8;
        const sh8 vv = *(const sh8*)((const char*)Lt + tl * 1024 + ((c16 * 16) ^ ((tl & 7) << 4)));
        *(sh8*)(orow + c16 * 8) = vv;
      }
    }
  }

  // V in place (layout already [d][t])
  #pragma unroll
  for (int rr = 0; rr < 4; ++rr) {
    const int d = tid + rr * 256;
    const int gi = (h * 48 + 32 + (d >> 6)) * 64 + (d & 63);
    const float g = gamma[gi], be = beta[gi];
    short* vrow = Vt + ((size_t)bh * 1024 + d) * 512 + t0;
    #pragma unroll
    for (int i = 0; i < 4; ++i) {
      sh8 vv = *(const sh8*)(vrow + i * 8);
      #pragma unroll
      for (int j = 0; j < 8; ++j) {
        const int tl = i * 8 + j;
        vv[j] = bf16r((b2f(vv[j]) - stats[tl][0]) * stats[tl][1] * g + be);
      }
      *(sh8*)(vrow + i * 8) = vv;
    }
  }
}

// ---------------------------------------------------------------------------
// k_qk: S = (Q.K)/32, lower-tri tiles only. 128x128 tile, BK=64.
__global__ __launch_bounds__(256) void k_qk(
    const short* __restrict__ Q, const short* __restrict__ K, float* __restrict__ S)
{
  const int bid = blockIdx.x;
  const int bh = bid / 10;
  const int j = bid - bh * 10;
  const int qi = (j >= 6) ? 3 : (j >= 3) ? 2 : (j >= 1) ? 1 : 0;
  const int ki = j - qi * (qi + 1) / 2;
  const int tid = threadIdx.x, lane = tid & 63, w = tid >> 6;
  const int wm = w >> 1, wn = w & 1;

  __shared__ short Qs[128 * 64];
  __shared__ short Ks[128 * 64];

  const short* Qg = Q + ((size_t)bh * 512 + qi * 128) * 1024;
  const short* Kg = K + ((size_t)bh * 512 + ki * 128) * 1024;

  fx4 acc[4][4];
  #pragma unroll
  for (int mi = 0; mi < 4; ++mi)
    #pragma unroll
    for (int ni = 0; ni < 4; ++ni) acc[mi][ni] = fx4{0.f, 0.f, 0.f, 0.f};

  for (int ks = 0; ks < 16; ++ks) {
    __syncthreads();
    const int row = tid & 127, kh = tid >> 7;
    #pragma unroll
    for (int i = 0; i < 4; ++i) {
      const int kl = kh * 32 + i * 8;
      const sh8 qv = *(const sh8*)(Qg + (size_t)row * 1024 + ks * 64 + kl);
      const sh8 kv = *(const sh8*)(Kg + (size_t)row * 1024 + ks * 64 + kl);
      *(sh8*)((char*)Qs + row * 128 + ((2 * kl) ^ ((row & 7) << 4))) = qv;
      *(sh8*)((char*)Ks + row * 128 + ((2 * kl) ^ ((row & 7) << 4))) = kv;
    }
    __syncthreads();
    #pragma unroll
    for (int ksub = 0; ksub < 2; ++ksub) {
      sh8 a[4], bf[4];
      #pragma unroll
      for (int mi = 0; mi < 4; ++mi) {
        const int r2 = wm * 64 + mi * 16 + (lane & 15);
        a[mi] = *(const sh8*)((const char*)Qs + r2 * 128 + ((ksub * 64 + (lane >> 4) * 16) ^ ((r2 & 7) << 4)));
      }
      #pragma unroll
      for (int ni = 0; ni < 4; ++ni) {
        const int r2 = wn * 64 + ni * 16 + (lane & 15);
        bf[ni] = *(const sh8*)((const char*)Ks + r2 * 128 + ((ksub * 64 + (lane >> 4) * 16) ^ ((r2 & 7) << 4)));
      }
      #pragma unroll
      for (int mi = 0; mi < 4; ++mi)
        #pragma unroll
        for (int ni = 0; ni < 4; ++ni)
          acc[mi][ni] = mfma_bf16(a[mi], bf[ni], acc[mi][ni]);
    }
  }

  float* Sg = S + (size_t)bh * 262144;
  const int q0 = qi * 128 + wm * 64, k0 = ki * 128 + wn * 64;
  #pragma unroll
  for (int mi = 0; mi < 4; ++mi)
    #pragma unroll
    for (int ni = 0; ni < 4; ++ni) {
      const int q = q0 + mi * 16 + (lane >> 4) * 4;
      const int kc = k0 + ni * 16 + (lane & 15);
      #pragma unroll
      for (int r = 0; r < 4; ++r)
        Sg[(size_t)(q + r) * 512 + kc] = acc[mi][ni][r] * 0.03125f;
    }
}

// ---------------------------------------------------------------------------
// k_softmax: causal softmax S(f32) -> Pb(bf16), zeros above diagonal.
__global__ __launch_bounds__(256) void k_softmax(const float* __restrict__ S,
                                                 short* __restrict__ Pb)
{
  const int row = blockIdx.x * 4 + (threadIdx.x >> 6);
  const int lane = threadIdx.x & 63;
  const int bh = row >> 9, q = row & 511;
  const float* Sr = S + (size_t)bh * 262144 + (size_t)q * 512;
  short* Pr = Pb + (size_t)bh * 262144 + (size_t)q * 512;
  const int n = q + 1;
  float v[8]; float mx = -1e30f;
  #pragma unroll
  for (int i = 0; i < 8; ++i) {
    const int k = lane + i * 64;
    v[i] = (k < n) ? Sr[k] : -1e30f;
    mx = fmaxf(mx, v[i]);
  }
  #pragma unroll
  for (int off = 32; off > 0; off >>= 1) mx = fmaxf(mx, __shfl_xor(mx, off));
  float sum = 0.f;
  #pragma unroll
  for (int i = 0; i < 8; ++i) {
    const float e = (v[i] > -1e29f) ? __expf(v[i] - mx) : 0.f;
    v[i] = e; sum += e;
  }
  #pragma unroll
  for (int off = 32; off > 0; off >>= 1) sum += __shfl_xor(sum, off);
  const float inv = 1.f / sum;
  #pragma unroll
  for (int i = 0; i < 8; ++i) Pr[lane + i * 64] = bf16r(v[i] * inv);
}

// ---------------------------------------------------------------------------
// k_pv: ctx = P @ V, BK=64; epilogue restages through LDS -> scrambled Cs.
__global__ __launch_bounds__(256) void k_pv(
    const short* __restrict__ Pb, const short* __restrict__ Vt, short* __restrict__ Cs)
{
  const int bid = blockIdx.x;
  const int bh = bid >> 5;
  const int qi = (bid >> 3) & 3, dt = bid & 7;
  const int tid = threadIdx.x, lane = tid & 63, w = tid >> 6;
  const int wm = w >> 1, wn = w & 1;

  __shared__ short Ps[128 * 64];
  __shared__ short Vs[128 * 64];
  __shared__ short ctile[128 * 128];   // [dl][ql] swizzled

  const short* Pg = Pb + ((size_t)bh * 512 + qi * 128) * 512;
  const short* Vg = Vt + ((size_t)bh * 1024 + dt * 128) * 512;

  fx4 acc[4][4];
  #pragma unroll
  for (int mi = 0; mi < 4; ++mi)
    #pragma unroll
    for (int ni = 0; ni < 4; ++ni) acc[mi][ni] = fx4{0.f, 0.f, 0.f, 0.f};

  const int nks = (qi + 1) * 2;
  for (int ks = 0; ks < nks; ++ks) {
    __syncthreads();
    const int row = tid & 127, kh = tid >> 7;
    #pragma unroll
    for (int i = 0; i < 4; ++i) {
      const int kl = kh * 32 + i * 8;
      const sh8 pv = *(const sh8*)(Pg + (size_t)row * 512 + ks * 64 + kl);
      const sh8 vv = *(const sh8*)(Vg + (size_t)row * 512 + ks * 64 + kl);
      *(sh8*)((char*)Ps + row * 128 + ((2 * kl) ^ ((row & 7) << 4))) = pv;
      *(sh8*)((char*)Vs + row * 128 + ((2 * kl) ^ ((row & 7) << 4))) = vv;
    }
    __syncthreads();
    #pragma unroll
    for (int ksub = 0; ksub < 2; ++ksub) {
      sh8 a[4], bf[4];
      #pragma unroll
      for (int mi = 0; mi < 4; ++mi) {
        const int r2 = wm * 64 + mi * 16 + (lane & 15);
        a[mi] = *(const sh8*)((const char*)Ps + r2 * 128 + ((ksub * 64 + (lane >> 4) * 16) ^ ((r2 & 7) << 4)));
      }
      #pragma unroll
      for (int ni = 0; ni < 4; ++ni) {
        const int r2 = wn * 64 + ni * 16 + (lane & 15);
        bf[ni] = *(const sh8*)((const char*)Vs + r2 * 128 + ((ksub * 64 + (lane >> 4) * 16) ^ ((r2 & 7) << 4)));
      }
      #pragma unroll
      for (int mi = 0; mi < 4; ++mi)
        #pragma unroll
        for (int ni = 0; ni < 4; ++ni)
          acc[mi][ni] = mfma_bf16(a[mi], bf[ni], acc[mi][ni]);
    }
  }

  // acc -> ctile[dl][ql]
  #pragma unroll
  for (int mi = 0; mi < 4; ++mi)
    #pragma unroll
    for (int ni = 0; ni < 4; ++ni) {
      const int ql = wm * 64 + mi * 16 + (lane >> 4) * 4;
      const int dl = wn * 64 + ni * 16 + (lane & 15);
      const int swz = (dl & 7) << 4;
      #pragma unroll
      for (int r = 0; r < 4; ++r)
        ctile[(dl * 256 + ((2 * (ql + r)) ^ swz)) >> 1] = bf16r(acc[mi][ni][r]);
    }
  __syncthreads();

  // scrambled write: c[b][C][t2][f2]
  const int b = bh >> 3, h = bh & 7;
  const int cl_loc = tid >> 7, fq = (tid >> 1) & 63, tg_loc = tid & 1;
  const int C = h * 16 + dt * 2 + cl_loc;
  const int t2 = fq * 8 + qi * 2 + tg_loc;
  const int dl = cl_loc * 64 + fq;
  const int swz = (dl & 7) << 4;
  short* dst = Cs + (((size_t)b * 128 + C) * 512 + t2) * 64;
  #pragma unroll
  for (int jj = 0; jj < 8; ++jj) {
    const sh8 vv = *(const sh8*)((const char*)ctile + dl * 256 + ((tg_loc * 128 + jj * 16) ^ swz));
    *(sh8*)(dst + jj * 8) = vv;
  }
}

// ---------------------------------------------------------------------------
// k_proj: per (b,t2): Y[128,64] = Wp @ C; bias+PReLU+LN; -> Otmp[b][o][t2][f2]
__global__ __launch_bounds__(512) void k_proj(
    const short* __restrict__ Cs, const short* __restrict__ wb,
    const float* __restrict__ bias, const float* __restrict__ alphap,
    const float* __restrict__ gamma, const float* __restrict__ beta,
    float* __restrict__ Otmp)
{
  const int bid = blockIdx.x;
  const int b = bid >> 9, t2 = bid & 511;
  const int tid = threadIdx.x, lane = tid & 63, w = tid >> 6;

  __shared__ short Xs[64 * 128];   // [f2][C] swizzled (256B rows)
  __shared__ float red[18];

  {
    const int C = tid & 127, fq = tid >> 7;
    const short* srow = Cs + (((size_t)b * 128 + C) * 512 + t2) * 64;
    #pragma unroll
    for (int i = 0; i < 2; ++i) {
      const int fc = fq * 2 + i;
      const sh8 vv = *(const sh8*)(srow + fc * 8);
      #pragma unroll
      for (int jj = 0; jj < 8; ++jj) {
        const int f2 = fc * 8 + jj;
        *((short*)((char*)Xs + f2 * 256 + ((2 * C) ^ ((f2 & 7) << 4)))) = vv[jj];
      }
    }
  }
  __syncthreads();

  const float alpha = alphap[0];
  fx4 acc[4];
  #pragma unroll
  for (int ni = 0; ni < 4; ++ni) acc[ni] = fx4{0.f, 0.f, 0.f, 0.f};

  #pragma unroll
  for (int ks = 0; ks < 4; ++ks) {
    const int o = w * 16 + (lane & 15);
    const sh8 a = *(const sh8*)(wb + o * 128 + ks * 32 + (lane >> 4) * 8);
    #pragma unroll
    for (int ni = 0; ni < 4; ++ni) {
      const int f2 = ni * 16 + (lane & 15);
      const sh8 bf = *(const sh8*)((const char*)Xs + f2 * 256 + ((ks * 64 + (lane >> 4) * 16) ^ ((f2 & 7) << 4)));
      acc[ni] = mfma_bf16(a, bf, acc[ni]);
    }
  }

  float s0 = 0.f, s1 = 0.f;
  const int ob = w * 16 + (lane >> 4) * 4;
  #pragma unroll
  for (int ni = 0; ni < 4; ++ni)
    #pragma unroll
    for (int r = 0; r < 4; ++r) {
      float v = acc[ni][r] + bias[ob + r];
      v = (v >= 0.f) ? v : alpha * v;
      acc[ni][r] = v;
      s0 += v; s1 += v * v;
    }
  #pragma unroll
  for (int off = 32; off > 0; off >>= 1) { s0 += __shfl_down(s0, off); s1 += __shfl_down(s1, off); }
  if (lane == 0) { red[w * 2] = s0; red[w * 2 + 1] = s1; }
  __syncthreads();
  if (tid == 0) {
    float a0 = 0.f, a1 = 0.f;
    for (int i2 = 0; i2 < 8; ++i2) { a0 += red[2 * i2]; a1 += red[2 * i2 + 1]; }
    const float mu = a0 / 8192.f;
    const float var = a1 / 8192.f - mu * mu;
    red[16] = mu; red[17] = rsqrtf(var + 1e-5f);
  }
  __syncthreads();
  const float mu = red[16], rstd = red[17];

  #pragma unroll
  for (int ni = 0; ni < 4; ++ni) {
    const int f2 = ni * 16 + (lane & 15);
    #pragma unroll
    for (int r = 0; r < 4; ++r) {
      const int o = ob + r;
      const float zz = (acc[ni][r] - mu) * rstd * gamma[o * 64 + f2] + beta[o * 64 + f2];
      Otmp[(((size_t)b * 128 + o) * 512 + t2) * 64 + f2] = zz;   // 64B f2-runs
    }
  }
}

// ---------------------------------------------------------------------------
// k_trans: Otmp[b][o][t2][f2] -> out[b][o][f2][t2] via LDS 64x64 tile
__global__ __launch_bounds__(256) void k_trans(const float* __restrict__ Otmp,
                                               float* __restrict__ out)
{
  const int bid = blockIdx.x;
  const int bo = bid >> 3, tt8 = bid & 7;
  const int t20 = tt8 * 64;
  const int tid = threadIdx.x;
  __shared__ float Ltr[64][65];
  {
    const int f2c = tid & 15, t2l0 = tid >> 4;
    #pragma unroll
    for (int it = 0; it < 4; ++it) {
      const int t2l = t2l0 + it * 16;
      const float4 fv = *(const float4*)(Otmp + ((size_t)bo * 512 + t20 + t2l) * 64 + f2c * 4);
      Ltr[f2c * 4 + 0][t2l] = fv.x;
      Ltr[f2c * 4 + 1][t2l] = fv.y;
      Ltr[f2c * 4 + 2][t2l] = fv.z;
      Ltr[f2c * 4 + 3][t2l] = fv.w;
    }
  }
  __syncthreads();
  {
    const int t2c = tid & 15, f2l0 = tid >> 4;
    #pragma unroll
    for (int it = 0; it < 4; ++it) {
      const int f2 = f2l0 + it * 16;
      float4 fv;
      fv.x = Ltr[f2][t2c * 4 + 0]; fv.y = Ltr[f2][t2c * 4 + 1];
      fv.z = Ltr[f2][t2c * 4 + 2]; fv.w = Ltr[f2][t2c * 4 + 3];
      *(float4*)(out + ((size_t)bo * 64 + f2) * 512 + t20 + t2c * 4) = fv;
    }
  }
}

// ---------------------------------------------------------------------------
extern "C" void kernel_launch(void* const* d_in, const int* in_sizes, int n_in,
                              void* d_out, int out_size, void* d_ws, size_t ws_size,
                              hipStream_t stream) {
  (void)in_sizes; (void)n_in; (void)out_size;
  const float* x          = (const float*)d_in[0];
  const float* qkv_w      = (const float*)d_in[1];
  const float* qkv_b      = (const float*)d_in[2];
  const float* qkv_alpha  = (const float*)d_in[3];
  const float* qkv_gamma  = (const float*)d_in[4];
  const float* qkv_beta   = (const float*)d_in[5];
  const float* proj_w     = (const float*)d_in[6];
  const float* proj_b     = (const float*)d_in[7];
  const float* proj_alpha = (const float*)d_in[8];
  const float* proj_gamma = (const float*)d_in[9];
  const float* proj_beta  = (const float*)d_in[10];
  float* out = (float*)d_out;

  // ws regions (lifetime-aliased), total = 167,903,232 B (known safe):
  //  R0 @0        : Qt(pre)  -> S(f32)   -> Otmp[0..33.5M)
  //  R1 @33.5M    : Kt(pre)  -> Pb(bf16) -> Otmp[33.5M..67M)
  //  R2 @67M      : Vt (normalized in place, lives to k_pv)
  //  R3 @100.7M   : Q(norm)  -> Cs
  //  R4 @134.2M   : K(norm)
  //  R5 @167.77M  : qwb(96KB) + pwb(32KB)
  //  Pstat (1MB)  : stashed in d_out, fully overwritten by k_trans
  char* ws = (char*)d_ws;
  short* Qt  = (short*)(ws + 0);
  short* Kt  = (short*)(ws + 33554432);
  short* Vt  = (short*)(ws + 67108864);
  short* Q   = (short*)(ws + 100663296);
  short* K   = (short*)(ws + 134217728);
  short* qwb = (short*)(ws + 167772160);
  short* pwb = (short*)(ws + 167870464);
  float* S    = (float*)(ws + 0);
  short* Pb   = (short*)(ws + 33554432);
  short* Cs   = (short*)(ws + 100663296);
  float* Otmp = (float*)(ws + 0);
  float* Pstat = (float*)d_out;
  if (ws_size < 167903232u) return;

  k_prep<<<192, 256, 0, stream>>>(qkv_w, proj_w, qwb, pwb);
  kA_qkv<<<1024, 512, 0, stream>>>(x, qwb, qkv_b, qkv_alpha, Qt, Kt, Vt, Pstat);
  kB_norm<<<512, 256, 0, stream>>>(Qt, Kt, Vt, Pstat, qkv_gamma, qkv_beta, Q, K);
  k_qk<<<320, 256, 0, stream>>>(Q, K, S);
  k_softmax<<<4096, 256, 0, stream>>>(S, Pb);
  k_pv<<<1024, 256, 0, stream>>>(Pb, Vt, Cs);
  k_proj<<<2048, 512, 0, stream>>>(Cs, pwb, proj_b, proj_alpha, proj_gamma, proj_beta, Otmp);
  k_trans<<<4096, 256, 0, stream>>>(Otmp, out);
}

// Round 3
// 241.348 us; speedup vs baseline: 2.2979x; 1.1561x over previous
//
#include <hip/hip_runtime.h>
#include <hip/hip_bf16.h>

#define T_ 512

using sh8 = __attribute__((ext_vector_type(8))) short;  // 8 bf16
using fx4 = __attribute__((ext_vector_type(4))) float;  // MFMA acc

__device__ __forceinline__ short bf16r(float x) {
  union { float f; unsigned u; } v; v.f = x;
  unsigned u = v.u;
  u += 0x7fffu + ((u >> 16) & 1u);   // RNE
  return (short)(u >> 16);
}
__device__ __forceinline__ float b2f(short s) {
  union { float f; unsigned u; } v; v.u = ((unsigned)(unsigned short)s) << 16;
  return v.f;
}
__device__ __forceinline__ fx4 mfma_bf16(sh8 a, sh8 b, fx4 c) {
  return __builtin_amdgcn_mfma_f32_16x16x32_bf16(a, b, c, 0, 0, 0);
}

// ---------------------------------------------------------------------------
// k_prep: weights f32->bf16; permuted gamma/beta tables.
//   gq/bq: [sect(2)][h(8)][d'=f*16+cl] for Q(sect0)/K(sect1) on-load LN.
//   gv/bv: [h(8)][d=cl*64+f] for V on-load LN.
__global__ __launch_bounds__(256) void k_prep(
    const float* __restrict__ qw, const float* __restrict__ pw,
    const float* __restrict__ gamma, const float* __restrict__ beta,
    short* __restrict__ qwb, short* __restrict__ pwb,
    float* __restrict__ gq, float* __restrict__ bq,
    float* __restrict__ gv, float* __restrict__ bv)
{
  const int i = blockIdx.x * 256 + threadIdx.x;
  if (i < 49152) qwb[i] = bf16r(qw[i]);
  if (i < 16384) pwb[i] = bf16r(pw[i]);
  if (i < 16384) {
    const int sh = i >> 10, dp = i & 1023;
    const int sect = sh >> 3, h = sh & 7;
    const int gi = (h * 48 + sect * 16 + (dp & 15)) * 64 + (dp >> 4);
    gq[i] = gamma[gi]; bq[i] = beta[gi];
  }
  if (i < 8192) {
    const int h = i >> 10, d = i & 1023;
    const int gi = (h * 48 + 32 + (d >> 6)) * 64 + (d & 63);
    gv[i] = gamma[gi]; bv[i] = beta[gi];
  }
}

// ---------------------------------------------------------------------------
// kA: per (b, f, t-tile 128): Y[384,128] = W @ X; bias+PReLU; column partial
//     sums -> Pstat; pre-norm bf16 -> Qp/Kp [bh][t][d'] (packed 8B stores),
//     Vt [bh][d][t].
__global__ __launch_bounds__(512) void kA_qkv(
    const float* __restrict__ x, const short* __restrict__ wb,
    const float* __restrict__ bias, const float* __restrict__ alphap,
    short* __restrict__ Qp, short* __restrict__ Kp, short* __restrict__ Vt,
    float* __restrict__ Pstat)
{
  const int bid = blockIdx.x;
  const int b = bid >> 8, f = (bid >> 2) & 63, tt = bid & 3;
  const int tid = threadIdx.x, lane = tid & 63, w = tid >> 6;

  __shared__ short Xs[128 * 128];   // [t][c], 256B pitch, swz ((t&7)<<4)
  __shared__ float psum[2048];

  // stage x: lanes along t (coalesced 256B runs), scalar transposed LDS writes
  {
    const int c0 = tid >> 5, tl = (tid & 31) * 2;
    const float* xb = x + ((size_t)(b * 128) * 64 + f) * 512 + tt * 128;
    #pragma unroll
    for (int p = 0; p < 8; ++p) {
      const int c = c0 + p * 16;
      const float* xp = xb + (size_t)c * 32768;
      #pragma unroll
      for (int q = 0; q < 2; ++q) {
        const int t = q * 64 + tl;
        const float2 fv = *(const float2*)(xp + t);
        *((short*)((char*)Xs + (t    ) * 256 + ((2 * c) ^ (((t    ) & 7) << 4)))) = bf16r(fv.x);
        *((short*)((char*)Xs + (t + 1) * 256 + ((2 * c) ^ (((t + 1) & 7) << 4)))) = bf16r(fv.y);
      }
    }
  }
  __syncthreads();

  const float alpha = alphap[0];
  fx4 acc[3][8];
  #pragma unroll
  for (int mi = 0; mi < 3; ++mi)
    #pragma unroll
    for (int ni = 0; ni < 8; ++ni) acc[mi][ni] = fx4{0.f, 0.f, 0.f, 0.f};

  // wave w = head h; mi = sect (q,k,v). K=128 over c, 4 steps.
  #pragma unroll
  for (int ks = 0; ks < 4; ++ks) {
    sh8 a[3];
    #pragma unroll
    for (int mi = 0; mi < 3; ++mi) {
      const int o = w * 48 + mi * 16 + (lane & 15);
      a[mi] = *(const sh8*)(wb + o * 128 + ks * 32 + (lane >> 4) * 8);
    }
    #pragma unroll
    for (int ni = 0; ni < 8; ++ni) {
      const int t = ni * 16 + (lane & 15);
      const sh8 bf = *(const sh8*)((const char*)Xs + t * 256 +
                     ((ks * 64 + (lane >> 4) * 16) ^ ((t & 7) << 4)));
      #pragma unroll
      for (int mi = 0; mi < 3; ++mi)
        acc[mi][ni] = mfma_bf16(a[mi], bf, acc[mi][ni]);
    }
  }

  // bias + PReLU + per-column (t) partial sums
  float s0[8], s1[8];
  #pragma unroll
  for (int ni = 0; ni < 8; ++ni) { s0[ni] = 0.f; s1[ni] = 0.f; }
  #pragma unroll
  for (int mi = 0; mi < 3; ++mi)
    #pragma unroll
    for (int r = 0; r < 4; ++r) {
      const int o = w * 48 + mi * 16 + (lane >> 4) * 4 + r;
      const float bo = bias[o];
      #pragma unroll
      for (int ni = 0; ni < 8; ++ni) {
        float v = acc[mi][ni][r] + bo;
        v = (v >= 0.f) ? v : alpha * v;
        acc[mi][ni][r] = v;
        s0[ni] += v; s1[ni] += v * v;
      }
    }
  #pragma unroll
  for (int ni = 0; ni < 8; ++ni) {
    float a0 = s0[ni], a1 = s1[ni];
    a0 += __shfl_down(a0, 32); a1 += __shfl_down(a1, 32);
    a0 += __shfl_down(a0, 16); a1 += __shfl_down(a1, 16);
    if (lane < 16) {
      psum[((w * 8 + ni) * 16 + lane) * 2 + 0] = a0;
      psum[((w * 8 + ni) * 16 + lane) * 2 + 1] = a1;
    }
  }
  __syncthreads();
  if (tid < 256) {
    const int col = tid & 127, s = tid >> 7;
    const int ni = col >> 4, l = col & 15;
    float a0 = 0.f;
    #pragma unroll
    for (int ww = 0; ww < 8; ++ww) a0 += psum[((ww * 8 + ni) * 16 + l) * 2 + s];
    Pstat[(size_t)s * 131072 + (size_t)b * 32768 + (size_t)f * 512 + tt * 128 + col] = a0;
  }

  // stores: Qp/Kp [bh][t][d'=f*16+cl] packed uint2 (4 consecutive d'); Vt [d][t]
  const int bh = b * 8 + w;
  #pragma unroll
  for (int mi = 0; mi < 2; ++mi) {
    short* dst = mi ? Kp : Qp;
    #pragma unroll
    for (int ni = 0; ni < 8; ++ni) {
      const int t = tt * 128 + ni * 16 + (lane & 15);
      const unsigned lo = (unsigned)(unsigned short)bf16r(acc[mi][ni][0]) |
                          ((unsigned)(unsigned short)bf16r(acc[mi][ni][1]) << 16);
      const unsigned hi = (unsigned)(unsigned short)bf16r(acc[mi][ni][2]) |
                          ((unsigned)(unsigned short)bf16r(acc[mi][ni][3]) << 16);
      uint2 pk; pk.x = lo; pk.y = hi;
      *(uint2*)(dst + ((size_t)bh * 512 + t) * 1024 + f * 16 + (lane >> 4) * 4) = pk;
    }
  }
  #pragma unroll
  for (int ni = 0; ni < 8; ++ni)
    #pragma unroll
    for (int r = 0; r < 4; ++r) {
      const int cl = (lane >> 4) * 4 + r;
      Vt[((size_t)bh * 1024 + cl * 64 + f) * 512 + tt * 128 + ni * 16 + (lane & 15)] =
          bf16r(acc[2][ni][r]);
    }
}

// ---------------------------------------------------------------------------
// k_stats: reduce Pstat over f -> MuRs[b][t] = {mu, rstd}
__global__ __launch_bounds__(256) void k_stats(const float* __restrict__ Pstat,
                                               float* __restrict__ MuRs)
{
  const int idx = blockIdx.x * 256 + threadIdx.x;   // grid 8 -> 2048
  const int b = idx >> 9, t = idx & 511;
  float s0 = 0.f, s1 = 0.f;
  for (int f = 0; f < 64; ++f) {
    s0 += Pstat[((size_t)b * 64 + f) * 512 + t];
    s1 += Pstat[131072 + ((size_t)b * 64 + f) * 512 + t];
  }
  const float mu = s0 * (1.f / 24576.f);
  const float var = s1 * (1.f / 24576.f) - mu * mu;
  MuRs[idx * 2] = mu;
  MuRs[idx * 2 + 1] = rsqrtf(var + 1e-5f);
}

// ---------------------------------------------------------------------------
// k_qk: S = (Qn.Kn)/32, lower-tri tiles, BK=128; LN applied on load.
__global__ __launch_bounds__(256) void k_qk(
    const short* __restrict__ Qp, const short* __restrict__ Kp,
    const float* __restrict__ MuRs, const float* __restrict__ gq,
    const float* __restrict__ bq, float* __restrict__ S)
{
  const int bid = blockIdx.x;
  const int bh = bid / 10;
  const int j = bid - bh * 10;
  const int qi = (j >= 6) ? 3 : (j >= 3) ? 2 : (j >= 1) ? 1 : 0;
  const int ki = j - qi * (qi + 1) / 2;
  const int b = bh >> 3, h = bh & 7;
  const int tid = threadIdx.x, lane = tid & 63, w = tid >> 6;
  const int wm = w >> 1, wn = w & 1;

  __shared__ short Qs[128 * 128];   // [t][d'-chunk], 256B pitch, swz
  __shared__ short Ks[128 * 128];
  __shared__ float sQ[256], sK[256];

  if (tid < 128) {
    *(float2*)&sQ[tid * 2] = *(const float2*)(MuRs + ((size_t)b * 512 + qi * 128 + tid) * 2);
    *(float2*)&sK[tid * 2] = *(const float2*)(MuRs + ((size_t)b * 512 + ki * 128 + tid) * 2);
  }
  __syncthreads();

  const int op = tid >> 7;                      // 0: Q, 1: K
  const int rowslot = (tid >> 4) & 7, unit = tid & 15;
  const short* src = op ? (Kp + ((size_t)bh * 512 + ki * 128) * 1024)
                        : (Qp + ((size_t)bh * 512 + qi * 128) * 1024);
  const float* murs = op ? sK : sQ;
  short* dstl = op ? Ks : Qs;
  const float* gqp = gq + (size_t)(op * 8 + h) * 1024;
  const float* bqp = bq + (size_t)(op * 8 + h) * 1024;

  fx4 acc[4][4];
  #pragma unroll
  for (int mi = 0; mi < 4; ++mi)
    #pragma unroll
    for (int ni = 0; ni < 4; ++ni) acc[mi][ni] = fx4{0.f, 0.f, 0.f, 0.f};

  for (int ks = 0; ks < 8; ++ks) {
    float g8[8], b8[8];
    *(float4*)&g8[0] = *(const float4*)(gqp + ks * 128 + unit * 8);
    *(float4*)&g8[4] = *(const float4*)(gqp + ks * 128 + unit * 8 + 4);
    *(float4*)&b8[0] = *(const float4*)(bqp + ks * 128 + unit * 8);
    *(float4*)&b8[4] = *(const float4*)(bqp + ks * 128 + unit * 8 + 4);
    __syncthreads();
    #pragma unroll
    for (int rit = 0; rit < 16; ++rit) {
      const int row = rit * 8 + rowslot;
      const sh8 v = *(const sh8*)(src + (size_t)row * 1024 + ks * 128 + unit * 8);
      const float mu = murs[row * 2], rs = murs[row * 2 + 1];
      sh8 o;
      #pragma unroll
      for (int e = 0; e < 8; ++e)
        o[e] = bf16r((b2f(v[e]) - mu) * rs * g8[e] + b8[e]);
      *(sh8*)((char*)dstl + row * 256 + ((unit * 16) ^ ((row & 7) << 4))) = o;
    }
    __syncthreads();
    #pragma unroll
    for (int ksub = 0; ksub < 4; ++ksub) {
      sh8 a[4], bb[4];
      #pragma unroll
      for (int mi = 0; mi < 4; ++mi) {
        const int t = wm * 64 + mi * 16 + (lane & 15);
        a[mi] = *(const sh8*)((const char*)Qs + t * 256 +
                ((ksub * 64 + (lane >> 4) * 16) ^ ((t & 7) << 4)));
      }
      #pragma unroll
      for (int ni = 0; ni < 4; ++ni) {
        const int t = wn * 64 + ni * 16 + (lane & 15);
        bb[ni] = *(const sh8*)((const char*)Ks + t * 256 +
                 ((ksub * 64 + (lane >> 4) * 16) ^ ((t & 7) << 4)));
      }
      #pragma unroll
      for (int mi = 0; mi < 4; ++mi)
        #pragma unroll
        for (int ni = 0; ni < 4; ++ni)
          acc[mi][ni] = mfma_bf16(a[mi], bb[ni], acc[mi][ni]);
    }
  }

  float* Sg = S + (size_t)bh * 262144;
  const int q0 = qi * 128 + wm * 64, k0 = ki * 128 + wn * 64;
  #pragma unroll
  for (int mi = 0; mi < 4; ++mi)
    #pragma unroll
    for (int ni = 0; ni < 4; ++ni) {
      const int q = q0 + mi * 16 + (lane >> 4) * 4;
      const int kc = k0 + ni * 16 + (lane & 15);
      #pragma unroll
      for (int r = 0; r < 4; ++r)
        Sg[(size_t)(q + r) * 512 + kc] = acc[mi][ni][r] * 0.03125f;
    }
}

// ---------------------------------------------------------------------------
// k_softmax: causal softmax S(f32) -> Pb(bf16), zeros above diagonal.
__global__ __launch_bounds__(256) void k_softmax(const float* __restrict__ S,
                                                 short* __restrict__ Pb)
{
  const int row = blockIdx.x * 4 + (threadIdx.x >> 6);
  const int lane = threadIdx.x & 63;
  const int bh = row >> 9, q = row & 511;
  const float* Sr = S + (size_t)bh * 262144 + (size_t)q * 512;
  short* Pr = Pb + (size_t)bh * 262144 + (size_t)q * 512;
  const int n = q + 1;
  float v[8]; float mx = -1e30f;
  #pragma unroll
  for (int i = 0; i < 8; ++i) {
    const int k = lane + i * 64;
    v[i] = (k < n) ? Sr[k] : -1e30f;
    mx = fmaxf(mx, v[i]);
  }
  #pragma unroll
  for (int off = 32; off > 0; off >>= 1) mx = fmaxf(mx, __shfl_xor(mx, off));
  float sum = 0.f;
  #pragma unroll
  for (int i = 0; i < 8; ++i) {
    const float e = (v[i] > -1e29f) ? __expf(v[i] - mx) : 0.f;
    v[i] = e; sum += e;
  }
  #pragma unroll
  for (int off = 32; off > 0; off >>= 1) sum += __shfl_xor(sum, off);
  const float inv = 1.f / sum;
  #pragma unroll
  for (int i = 0; i < 8; ++i) Pr[lane + i * 64] = bf16r(v[i] * inv);
}

// ---------------------------------------------------------------------------
// k_pv: ctx = P @ Vn (V normalized on load), BK=64; LDS-restage -> Cs.
__global__ __launch_bounds__(256) void k_pv(
    const short* __restrict__ Pb, const short* __restrict__ Vt,
    const float* __restrict__ MuRs, const float* __restrict__ gv,
    const float* __restrict__ bv, short* __restrict__ Cs)
{
  const int bid = blockIdx.x;
  const int bh = bid >> 5, qi = (bid >> 3) & 3, dt = bid & 7;
  const int b = bh >> 3, h = bh & 7;
  const int tid = threadIdx.x, lane = tid & 63, w = tid >> 6;
  const int wm = w >> 1, wn = w & 1;

  __shared__ char smem[32768];
  short* Ps = (short*)smem;                // [128 q][64 k], 128B pitch
  short* Vs = (short*)(smem + 16384);      // [128 d][64 k]
  short* ctile = (short*)smem;             // [128 d][128 q] reuse after loop

  const short* Pg = Pb + ((size_t)bh * 512 + qi * 128) * 512;
  const short* Vg = Vt + ((size_t)bh * 1024 + dt * 128) * 512;
  const float* gvp = gv + (size_t)h * 1024 + dt * 128;
  const float* bvp = bv + (size_t)h * 1024 + dt * 128;
  const float* mrp = MuRs + (size_t)b * 1024;

  const int rowslot = tid >> 3, unit = tid & 7;

  fx4 acc[4][4];
  #pragma unroll
  for (int mi = 0; mi < 4; ++mi)
    #pragma unroll
    for (int ni = 0; ni < 4; ++ni) acc[mi][ni] = fx4{0.f, 0.f, 0.f, 0.f};

  const int nks = (qi + 1) * 2;
  for (int ks = 0; ks < nks; ++ks) {
    float mr[16];   // {mu,rs} for k = ks*64 + unit*8 + e
    *(float4*)&mr[0]  = *(const float4*)(mrp + (ks * 64 + unit * 8) * 2);
    *(float4*)&mr[4]  = *(const float4*)(mrp + (ks * 64 + unit * 8) * 2 + 4);
    *(float4*)&mr[8]  = *(const float4*)(mrp + (ks * 64 + unit * 8) * 2 + 8);
    *(float4*)&mr[12] = *(const float4*)(mrp + (ks * 64 + unit * 8) * 2 + 12);
    __syncthreads();
    #pragma unroll
    for (int rit = 0; rit < 4; ++rit) {
      const int row = rit * 32 + rowslot;
      const sh8 p = *(const sh8*)(Pg + (size_t)row * 512 + ks * 64 + unit * 8);
      *(sh8*)((char*)Ps + row * 128 + ((unit * 16) ^ ((row & 7) << 4))) = p;
      const sh8 vv = *(const sh8*)(Vg + (size_t)row * 512 + ks * 64 + unit * 8);
      const float g = gvp[row], be = bvp[row];
      sh8 o;
      #pragma unroll
      for (int e = 0; e < 8; ++e)
        o[e] = bf16r((b2f(vv[e]) - mr[e * 2]) * mr[e * 2 + 1] * g + be);
      *(sh8*)((char*)Vs + row * 128 + ((unit * 16) ^ ((row & 7) << 4))) = o;
    }
    __syncthreads();
    #pragma unroll
    for (int ksub = 0; ksub < 2; ++ksub) {
      sh8 a[4], bb[4];
      #pragma unroll
      for (int mi = 0; mi < 4; ++mi) {
        const int r2 = wm * 64 + mi * 16 + (lane & 15);
        a[mi] = *(const sh8*)((const char*)Ps + r2 * 128 +
                ((ksub * 64 + (lane >> 4) * 16) ^ ((r2 & 7) << 4)));
      }
      #pragma unroll
      for (int ni = 0; ni < 4; ++ni) {
        const int r2 = wn * 64 + ni * 16 + (lane & 15);
        bb[ni] = *(const sh8*)((const char*)Vs + r2 * 128 +
                 ((ksub * 64 + (lane >> 4) * 16) ^ ((r2 & 7) << 4)));
      }
      #pragma unroll
      for (int mi = 0; mi < 4; ++mi)
        #pragma unroll
        for (int ni = 0; ni < 4; ++ni)
          acc[mi][ni] = mfma_bf16(a[mi], bb[ni], acc[mi][ni]);
    }
  }
  __syncthreads();   // protect Ps/Vs reads before ctile overwrite

  #pragma unroll
  for (int mi = 0; mi < 4; ++mi)
    #pragma unroll
    for (int ni = 0; ni < 4; ++ni) {
      const int ql = wm * 64 + mi * 16 + (lane >> 4) * 4;
      const int dl = wn * 64 + ni * 16 + (lane & 15);
      const int swz = (dl & 7) << 4;
      #pragma unroll
      for (int r = 0; r < 4; ++r)
        ctile[(dl * 256 + ((2 * (ql + r)) ^ swz)) >> 1] = bf16r(acc[mi][ni][r]);
    }
  __syncthreads();

  // scrambled write: c[b][C][t2][f2] in 128B f2-runs
  const int cl_loc = tid >> 7, fq = (tid >> 1) & 63, tg_loc = tid & 1;
  const int C = h * 16 + dt * 2 + cl_loc;
  const int t2 = fq * 8 + qi * 2 + tg_loc;
  const int dl = cl_loc * 64 + fq;
  const int swz = (dl & 7) << 4;
  short* dst = Cs + (((size_t)b * 128 + C) * 512 + t2) * 64;
  #pragma unroll
  for (int jj = 0; jj < 8; ++jj) {
    const sh8 vv = *(const sh8*)((const char*)ctile + dl * 256 + ((tg_loc * 128 + jj * 16) ^ swz));
    *(sh8*)(dst + jj * 8) = vv;
  }
}

// ---------------------------------------------------------------------------
// k_proj: per (b,t2): Y[128,64] = Wp @ C; bias+PReLU+LN; -> Otmp bf16 [b][o][t2][f2]
__global__ __launch_bounds__(512) void k_proj(
    const short* __restrict__ Cs, const short* __restrict__ wb,
    const float* __restrict__ bias, const float* __restrict__ alphap,
    const float* __restrict__ gamma, const float* __restrict__ beta,
    short* __restrict__ Otmpb)
{
  const int bid = blockIdx.x;
  const int b = bid >> 9, t2 = bid & 511;
  const int tid = threadIdx.x, lane = tid & 63, w = tid >> 6;

  __shared__ short Xs[64 * 128];   // [f2][C], 256B pitch, swz
  __shared__ float red[18];

  {
    const int rowslot = tid >> 3, unit = tid & 7;
    #pragma unroll
    for (int rit = 0; rit < 2; ++rit) {
      const int C = rit * 64 + rowslot;
      const sh8 vv = *(const sh8*)(Cs + (((size_t)b * 128 + C) * 512 + t2) * 64 + unit * 8);
      #pragma unroll
      for (int jj = 0; jj < 8; ++jj) {
        const int f2 = unit * 8 + jj;
        *((short*)((char*)Xs + f2 * 256 + ((2 * C) ^ ((f2 & 7) << 4)))) = vv[jj];
      }
    }
  }
  __syncthreads();

  const float alpha = alphap[0];
  fx4 acc[4];
  #pragma unroll
  for (int ni = 0; ni < 4; ++ni) acc[ni] = fx4{0.f, 0.f, 0.f, 0.f};

  #pragma unroll
  for (int ks = 0; ks < 4; ++ks) {
    const int o = w * 16 + (lane & 15);
    const sh8 a = *(const sh8*)(wb + o * 128 + ks * 32 + (lane >> 4) * 8);
    #pragma unroll
    for (int ni = 0; ni < 4; ++ni) {
      const int f2 = ni * 16 + (lane & 15);
      const sh8 bf = *(const sh8*)((const char*)Xs + f2 * 256 +
                     ((ks * 64 + (lane >> 4) * 16) ^ ((f2 & 7) << 4)));
      acc[ni] = mfma_bf16(a, bf, acc[ni]);
    }
  }

  float s0 = 0.f, s1 = 0.f;
  const int ob = w * 16 + (lane >> 4) * 4;
  #pragma unroll
  for (int ni = 0; ni < 4; ++ni)
    #pragma unroll
    for (int r = 0; r < 4; ++r) {
      float v = acc[ni][r] + bias[ob + r];
      v = (v >= 0.f) ? v : alpha * v;
      acc[ni][r] = v;
      s0 += v; s1 += v * v;
    }
  #pragma unroll
  for (int off = 32; off > 0; off >>= 1) { s0 += __shfl_down(s0, off); s1 += __shfl_down(s1, off); }
  if (lane == 0) { red[w * 2] = s0; red[w * 2 + 1] = s1; }
  __syncthreads();
  if (tid == 0) {
    float a0 = 0.f, a1 = 0.f;
    for (int i2 = 0; i2 < 8; ++i2) { a0 += red[2 * i2]; a1 += red[2 * i2 + 1]; }
    const float mu = a0 / 8192.f;
    const float var = a1 / 8192.f - mu * mu;
    red[16] = mu; red[17] = rsqrtf(var + 1e-5f);
  }
  __syncthreads();
  const float mu = red[16], rstd = red[17];

  #pragma unroll
  for (int ni = 0; ni < 4; ++ni) {
    const int f2 = ni * 16 + (lane & 15);
    #pragma unroll
    for (int r = 0; r < 4; ++r) {
      const int o = ob + r;
      const float zz = (acc[ni][r] - mu) * rstd * gamma[o * 64 + f2] + beta[o * 64 + f2];
      Otmpb[(((size_t)b * 128 + o) * 512 + t2) * 64 + f2] = bf16r(zz);
    }
  }
}

// ---------------------------------------------------------------------------
// k_trans: Otmp bf16 [b][o][t2][f2] -> out f32 [b][o][f2][t2]
__global__ __launch_bounds__(256) void k_trans(const short* __restrict__ Otmpb,
                                               float* __restrict__ out)
{
  const int bid = blockIdx.x;
  const int bo = bid >> 3, tt8 = bid & 7;
  const int t20 = tt8 * 64;
  const int tid = threadIdx.x;
  __shared__ float Ltr[64 * 68];   // [f2][t2], pitch 68

  {
    const int t2l = tid >> 2, u = tid & 3;
    const short* srow = Otmpb + ((size_t)bo * 512 + t20 + t2l) * 64 + u * 16;
    const sh8 v0 = *(const sh8*)(srow);
    const sh8 v1 = *(const sh8*)(srow + 8);
    #pragma unroll
    for (int e = 0; e < 8; ++e) {
      Ltr[(u * 16 + e) * 68 + t2l]     = b2f(v0[e]);
      Ltr[(u * 16 + 8 + e) * 68 + t2l] = b2f(v1[e]);
    }
  }
  __syncthreads();
  {
    const int f2 = tid >> 2, u = tid & 3;
    float* dst = out + ((size_t)bo * 64 + f2) * 512 + t20 + u * 16;
    #pragma unroll
    for (int k = 0; k < 4; ++k)
      *(float4*)(dst + k * 4) = *(const float4*)&Ltr[f2 * 68 + u * 16 + k * 4];
  }
}

// ---------------------------------------------------------------------------
extern "C" void kernel_launch(void* const* d_in, const int* in_sizes, int n_in,
                              void* d_out, int out_size, void* d_ws, size_t ws_size,
                              hipStream_t stream) {
  (void)in_sizes; (void)n_in; (void)out_size;
  const float* x          = (const float*)d_in[0];
  const float* qkv_w      = (const float*)d_in[1];
  const float* qkv_b      = (const float*)d_in[2];
  const float* qkv_alpha  = (const float*)d_in[3];
  const float* qkv_gamma  = (const float*)d_in[4];
  const float* qkv_beta   = (const float*)d_in[5];
  const float* proj_w     = (const float*)d_in[6];
  const float* proj_b     = (const float*)d_in[7];
  const float* proj_alpha = (const float*)d_in[8];
  const float* proj_gamma = (const float*)d_in[9];
  const float* proj_beta  = (const float*)d_in[10];
  float* out = (float*)d_out;

  // ws (lifetime-aliased, total 167,903,232 B known safe):
  //  Qp @0 (33.5M) [kA->k_qk]        ; Cs   @0 after k_qk
  //  Kp @33.5M     [kA->k_qk]        ; Otmp @33.5M after k_qk
  //  Vt @67M       [kA->k_pv]
  //  S  @100.7M f32 [k_qk->k_softmax]
  //  Pb @134.2M bf16 16.8M [k_softmax->k_pv]
  //  MuRs @150994944 (16KB); gq/bq/gv/bv tables after it
  //  qwb @167772160, pwb @167870464
  //  Pstat (1MB): stashed in d_out, fully overwritten by k_trans
  char* ws = (char*)d_ws;
  short* Qp   = (short*)(ws + 0);
  short* Kp   = (short*)(ws + 33554432);
  short* Vt   = (short*)(ws + 67108864);
  float* S    = (float*)(ws + 100663296);
  short* Pb   = (short*)(ws + 134217728);
  float* MuRs = (float*)(ws + 150994944);
  float* gq   = (float*)(ws + 151011328);
  float* bq   = (float*)(ws + 151076864);
  float* gv   = (float*)(ws + 151142400);
  float* bv   = (float*)(ws + 151175168);
  short* Cs    = (short*)(ws + 0);
  short* Otmpb = (short*)(ws + 33554432);
  short* qwb  = (short*)(ws + 167772160);
  short* pwb  = (short*)(ws + 167870464);
  float* Pstat = (float*)d_out;
  if (ws_size < 167903232u) return;

  k_prep<<<192, 256, 0, stream>>>(qkv_w, proj_w, qkv_gamma, qkv_beta,
                                  qwb, pwb, gq, bq, gv, bv);
  kA_qkv<<<1024, 512, 0, stream>>>(x, qwb, qkv_b, qkv_alpha, Qp, Kp, Vt, Pstat);
  k_stats<<<8, 256, 0, stream>>>(Pstat, MuRs);
  k_qk<<<320, 256, 0, stream>>>(Qp, Kp, MuRs, gq, bq, S);
  k_softmax<<<4096, 256, 0, stream>>>(S, Pb);
  k_pv<<<1024, 256, 0, stream>>>(Pb, Vt, MuRs, gv, bv, Cs);
  k_proj<<<2048, 512, 0, stream>>>(Cs, pwb, proj_b, proj_alpha, proj_gamma, proj_beta, Otmpb);
  k_trans<<<4096, 256, 0, stream>>>(Otmpb, out);
}